// Round 6
// baseline (218.461 us; speedup 1.0000x reference)
//
#include <hip/hip_runtime.h>

#define B_    16
#define CIN   64
#define COUT  128
#define H_    32
#define W_    32
#define HP    34           // halo-padded spatial dim
#define XROW  2176         // shorts per padded qx row = 272 chunks * 8

typedef __attribute__((ext_vector_type(8)))  short  short8;    // 8 bf16 = 4 VGPRs
typedef __attribute__((ext_vector_type(16))) float  float16v;  // 32x32 MFMA C/D

#define MAGTAG 0x7E57C0DEull   // high-word tag: != 0xAAAAAAAA poison

// float -> bf16 bits; exact for small integers (|q| <= 127 needs 7 mantissa bits)
__device__ __forceinline__ unsigned short f2bf(float q) {
  return (unsigned short)(__builtin_bit_cast(unsigned int, q) >> 16);
}

// publish {MAGTAG, v} with agent-scope release (orders prior plain stores)
__device__ __forceinline__ void pub(unsigned long long* p, unsigned int v) {
  __hip_atomic_exchange(p, (MAGTAG << 32) | (unsigned long long)v,
                        __ATOMIC_RELEASE, __HIP_MEMORY_SCOPE_AGENT);
}
// spin until slot is tagged; agent-scope acquire; returns payload
__device__ __forceinline__ unsigned int pollv(unsigned long long* p) {
  unsigned long long v =
      __hip_atomic_load(p, __ATOMIC_ACQUIRE, __HIP_MEMORY_SCOPE_AGENT);
  while ((v >> 32) != MAGTAG) {
    __builtin_amdgcn_s_sleep(2);
    v = __hip_atomic_load(p, __ATOMIC_ACQUIRE, __HIP_MEMORY_SCOPE_AGENT);
  }
  return (unsigned int)v;
}

__device__ __forceinline__ float max4(float4 v) {
  return fmaxf(fmaxf(fabsf(v.x), fabsf(v.y)), fmaxf(fabsf(v.z), fabsf(v.w)));
}

// block-wide max; result valid in ALL threads. Barrier-safe for reuse.
__device__ __forceinline__ float blk_max(float m, int t, volatile float* sred) {
#pragma unroll
  for (int off = 32; off > 0; off >>= 1)
    m = fmaxf(m, __shfl_down(m, off, 64));
  if ((t & 63) == 0) sred[t >> 6] = m;
  __syncthreads();
  const float r = fmaxf(fmaxf(sred[0], sred[1]), fmaxf(sred[2], sred[3]));
  __syncthreads();
  return r;
}

// ---------------------------------------------------------------------------
// Single megakernel, 576 blocks (all co-resident at 4 blocks/CU):
//   Phase A: blocks [0,512) partial max|x| (512 float4 each) -> slotA[bid];
//            [512,544) partial max|w| (576 float4 each)      -> slotA[bid];
//            [544,576) zero qx halo rows, pub slotB, exit (575 stays: reducer).
//   Block 575: polls slotA[0..543], reduces, pubs finalX/finalW; then polls
//              slotB[0..574], pubs flagB; exits.
//   Phase B: [0,512) quantize+pack x row (b=bid>>5, y=bid&31) into qx
//            (bit-identical R4 math/layout); [512,544) quantize+pack 1/32 of
//            qw. Both pub slotB.
//   Phase C: [0,512) poll flagB, then R4's 32x32x16 bf16 MFMA conv (exact:
//            integer operands, partials < 2^24), write out.
// Layouts: qx bf16 [B][y:34][k16:4][kb:2][xs:34][8cin]; qw [s:9][k16:4][kb:2]
// [cout:128][8cin]. D: col=lane&31 (x), row=(reg&3)+8*(reg>>2)+4*(lane>>5).
// ---------------------------------------------------------------------------
__global__ __launch_bounds__(256, 4) void mega_kernel(
    const float* __restrict__ x, const float* __restrict__ w,
    const float* __restrict__ bias, float* __restrict__ out,
    unsigned long long* __restrict__ sync,
    unsigned short* __restrict__ qx, unsigned short* __restrict__ qw) {
  __shared__ float sred[4];
  __shared__ float lsc[2];
  __shared__ __align__(16) unsigned short lds[32 * 72];  // pack transpose
  const int t   = threadIdx.x;
  const int bid = blockIdx.x;

  // ---------------- Phase A ----------------
  if (bid < 512) {
    const float4* x4 = (const float4*)x;
    float m = fmaxf(max4(x4[bid * 512 + t]), max4(x4[bid * 512 + 256 + t]));
    m = blk_max(m, t, sred);
    if (t == 0) pub(&sync[bid], __float_as_uint(m));
  } else if (bid < 544) {
    const float4* w4 = (const float4*)w;
    const int base = (bid - 512) * 576;
    float m = fmaxf(max4(w4[base + t]), max4(w4[base + 256 + t]));
    if (t < 64) m = fmaxf(m, max4(w4[base + 512 + t]));
    m = blk_max(m, t, sred);
    if (t == 0) pub(&sync[bid], __float_as_uint(m));
  } else {
    // zero halo rows: j -> (b, yy in {0,33})
    const int j = bid - 544;
    const int b = j >> 1, yy = (j & 1) ? 33 : 0;
    const size_t row = (size_t)(b * HP + yy) * XROW;
    uint4 z; z.x = z.y = z.z = z.w = 0;
    for (int c = t; c < 272; c += 256)
      *(uint4*)(qx + row + (size_t)c * 8) = z;
    __syncthreads();
    if (t == 0) { __threadfence(); pub(&sync[578 + bid], 0); }
    if (bid != 575) return;
    // ---- block 575: A-reduce ----
    float mx = 0.0f, mw = 0.0f;
    for (int jj = t; jj < 544; jj += 256) {
      const float f = __uint_as_float(pollv(&sync[jj]));
      if (jj < 512) mx = fmaxf(mx, f); else mw = fmaxf(mw, f);
    }
    mx = blk_max(mx, t, sred);
    mw = blk_max(mw, t, sred);
    if (t == 0) {
      pub(&sync[576], __float_as_uint(mx));
      pub(&sync[577], __float_as_uint(mw));
    }
    // ---- B-reduce -> flagB ----
    for (int jj = t; jj < 575; jj += 256) (void)pollv(&sync[578 + jj]);
    __syncthreads();
    if (t == 0) pub(&sync[1154], 0);
    return;
  }

  // wait for finals (one poller per block, LDS broadcast)
  if (t == 0) {
    lsc[0] = __uint_as_float(pollv(&sync[576]));
    lsc[1] = __uint_as_float(pollv(&sync[577]));
  }
  __syncthreads();
  const float mx = lsc[0], mw = lsc[1];

  // ---------------- Phase B ----------------
  if (bid < 512) {
    const int b = bid >> 5, y = bid & 31;
    const float s = mx / 127.0f;
#pragma unroll
    for (int k = 0; k < 8; ++k) {
      const int u = t + k * 256;            // [0, 2048)
      const int cin = u >> 5, xx = u & 31;  // coalesced along x
      float q = rintf(x[((b * CIN + cin) * H_ + y) * W_ + xx] / s);
      q = fminf(fmaxf(q, -127.0f), 127.0f);
      lds[xx * 72 + cin] = f2bf(q);
    }
    __syncthreads();
    const size_t row = (size_t)(b * HP + y + 1) * XROW;
    for (int c = t; c < 272; c += 256) {
      const int k16 = c / 68;
      const int r   = c - k16 * 68;
      const int kbh = r / 34;
      const int xs  = r - kbh * 34;
      uint4 v; v.x = v.y = v.z = v.w = 0;
      if (xs >= 1 && xs <= 32)
        v = *(const uint4*)(&lds[(xs - 1) * 72 + k16 * 16 + kbh * 8]);
      *(uint4*)(qx + row + (size_t)c * 8) = v;
    }
    __syncthreads();
    if (t == 0) { __threadfence(); pub(&sync[578 + bid], 0); }
  } else {
    // w-quant: this block's 2304-element slice
    const float s = mw / 127.0f;
    const int base = (bid - 512) * 2304;
#pragma unroll
    for (int mIt = 0; mIt < 9; ++mIt) {
      const int i = base + t + mIt * 256;
      float q = rintf(w[i] / s);
      q = fminf(fmaxf(q, -127.0f), 127.0f);
      // i = ((o*64 + c)*3 + kh)*3 + kw
      const int kw = i % 3; int j2 = i / 3;
      const int kh = j2 % 3; j2 /= 3;
      const int c = j2 & 63; const int o = j2 >> 6;
      const int sidx = kh * 3 + kw;
      const int k16 = c >> 4, kb2 = (c >> 3) & 1, e = c & 7;
      qw[(size_t)(((sidx * 4 + k16) * 2 + kb2) * 128 + o) * 8 + e] = f2bf(q);
    }
    __syncthreads();
    if (t == 0) { __threadfence(); pub(&sync[578 + bid], 0); }
    return;
  }

  // wait for all packs (halo + w + rows) before conv
  if (t == 0) (void)pollv(&sync[1154]);
  __syncthreads();

  // ---------------- Phase C: conv ----------------
  const int lane = t & 63;
  const int wv   = t >> 6;            // cout group
  const int col  = lane & 31;         // pixel x (B) / cout row (A)
  const int kb   = lane >> 5;         // k-half
  const int y    = bid & 31;
  const int b    = bid >> 5;
  const int co0  = wv * 32;

  float16v acc0 = (float16v)0.0f, acc1 = (float16v)0.0f;
  const unsigned short* __restrict__ xp =
      qx + (size_t)b * HP * XROW + kb * 272 + col * 8;
  const unsigned short* __restrict__ wp = qw + kb * 1024 + (co0 + col) * 8;

#pragma unroll
  for (int kh = 0; kh < 3; ++kh) {
    const unsigned short* __restrict__ xr = xp + (size_t)(y + kh) * XROW;
#pragma unroll
    for (int kw = 0; kw < 3; ++kw) {
      const int s = kh * 3 + kw;
#pragma unroll
      for (int k16 = 0; k16 < 4; ++k16) {
        short8 a  = *(const short8*)(wp + (s * 4 + k16) * 2048);
        short8 bf = *(const short8*)(xr + k16 * 544 + kw * 8);
        if (((s * 4 + k16) & 1) == 0)
          acc0 = __builtin_amdgcn_mfma_f32_32x32x16_bf16(a, bf, acc0, 0, 0, 0);
        else
          acc1 = __builtin_amdgcn_mfma_f32_32x32x16_bf16(a, bf, acc1, 0, 0, 0);
      }
    }
  }

  const float sc = (mx / 127.0f) * (mw / 127.0f);
  const float16v acc = acc0 + acc1;
#pragma unroll
  for (int r = 0; r < 16; ++r) {
    const int row  = (r & 3) + 8 * (r >> 2) + 4 * kb;
    const int cout = co0 + row;
    out[((b * COUT + cout) << 10) + y * W_ + col] = sc * acc[r] + bias[cout];
  }
}

// ---------------------------------------------------------------------------
extern "C" void kernel_launch(void* const* d_in, const int* in_sizes, int n_in,
                              void* d_out, int out_size, void* d_ws, size_t ws_size,
                              hipStream_t stream) {
  const float* x    = (const float*)d_in[0];
  const float* w    = (const float*)d_in[1];
  const float* bias = (const float*)d_in[2];
  float* out = (float*)d_out;

  // ws: sync u64[1160] | (16 KiB align) qx bf16 [16][34][272][8] | qw bf16 147 KB
  unsigned long long* syncp = (unsigned long long*)d_ws;
  unsigned short* qx = (unsigned short*)((char*)d_ws + 16384);
  unsigned short* qw = qx + (size_t)B_ * HP * XROW;

  mega_kernel<<<576, 256, 0, stream>>>(x, w, bias, out, syncp, qx, qw);
}

// Round 7
// 68.432 us; speedup vs baseline: 3.1924x; 3.1924x over previous
//
#include <hip/hip_runtime.h>

#define B_    16
#define CIN   64
#define COUT  128
#define H_    32
#define W_    32
#define HP    34            // halo-padded spatial dim
#define XCH   136           // 16B chunks per padded qx row = 2*2*34
#define NPB   256           // maxabs grid blocks

typedef __attribute__((ext_vector_type(4)))  int int4v;    // 16 int8 = 4 VGPRs
typedef __attribute__((ext_vector_type(16))) int int16v;   // 32x32 i8 MFMA C/D

// All-lanes max of a 256-entry array (written by maxabs), no LDS, no sync.
__device__ __forceinline__ float wave_max256(const float* __restrict__ p) {
  const int lane = threadIdx.x & 63;
  float m = fmaxf(fmaxf(p[lane], p[lane + 64]),
                  fmaxf(p[lane + 128], p[lane + 192]));
#pragma unroll
  for (int off = 32; off > 0; off >>= 1)
    m = fmaxf(m, __shfl_down(m, off, 64));
  return __shfl(m, 0, 64);
}

// ---------------------------------------------------------------------------
// Stage 1: per-block max|x|, max|w| -> bmx[256], bmw[256] (plain stores, no
// init needed, poison-safe). float4 loads, 256 blocks = 1 per CU.
// ---------------------------------------------------------------------------
__global__ __launch_bounds__(256) void maxabs_kernel(
    const float4* __restrict__ x4, const float4* __restrict__ w4,
    float* __restrict__ bmx, float* __restrict__ bmw) {
  const int nw4 = COUT * CIN * 9 / 4;       // 18432
  const int tid = blockIdx.x * 256 + threadIdx.x;
  float mx = 0.0f, mw = 0.0f;
#pragma unroll
  for (int k = 0; k < 4; ++k) {             // 262144 float4 / 65536 = 4
    float4 v = x4[tid + k * 65536];
    mx = fmaxf(mx, fmaxf(fmaxf(fabsf(v.x), fabsf(v.y)),
                         fmaxf(fabsf(v.z), fabsf(v.w))));
  }
  if (tid < nw4) {
    float4 v = w4[tid];
    mw = fmaxf(mw, fmaxf(fmaxf(fabsf(v.x), fabsf(v.y)),
                         fmaxf(fabsf(v.z), fabsf(v.w))));
  }
#pragma unroll
  for (int off = 32; off > 0; off >>= 1) {
    mx = fmaxf(mx, __shfl_down(mx, off, 64));
    mw = fmaxf(mw, __shfl_down(mw, off, 64));
  }
  __shared__ float smx[4], smw[4];
  const int wid = threadIdx.x >> 6;
  if ((threadIdx.x & 63) == 0) { smx[wid] = mx; smw[wid] = mw; }
  __syncthreads();
  if (threadIdx.x == 0) {
#pragma unroll
    for (int i = 1; i < 4; ++i) { mx = fmaxf(mx, smx[i]); mw = fmaxf(mw, smw[i]); }
    bmx[blockIdx.x] = mx;
    bmw[blockIdx.x] = mw;
  }
}

// ---------------------------------------------------------------------------
// Stage 2 (fused): quantize exactly like the reference (IEEE div by max/127,
// rintf = round-half-even, clip +-127) and pack INT8 in i8-MFMA lane order:
//   qx: s8 [B][y:34][c32:2][kb:2][xs:34][16 cin]   (halo-padded)
//   qw: s8 [s:9][c32:2][kb:2][cout:128][16 cin]
// (lane holds 16 contiguous cin for k = kb*16+j within the c32 half)
// Blocks [0,512): one (b,y) row of x.  [512,544): zero halo rows.
// [544,832): weights.
// ---------------------------------------------------------------------------
__global__ __launch_bounds__(256) void quant_pack_kernel(
    const float* __restrict__ x, const float* __restrict__ w,
    const float* __restrict__ bmx, const float* __restrict__ bmw,
    char* __restrict__ qx, char* __restrict__ qw) {
  __shared__ __align__(16) char lds[W_ * 80];  // [x][cin], pad 64->80 (16-aligned)
  const int t = threadIdx.x;
  const int bb = blockIdx.x;
  if (bb < 512) {
    const int b = bb >> 5, y = bb & 31;
    const float s = wave_max256(bmx) / 127.0f;
#pragma unroll
    for (int k = 0; k < 8; ++k) {
      const int u = t + k * 256;            // [0, 2048)
      const int cin = u >> 5, xx = u & 31;  // coalesced along x
      float q = rintf(x[((b * CIN + cin) * H_ + y) * W_ + xx] / s);
      q = fminf(fmaxf(q, -127.0f), 127.0f);
      lds[xx * 80 + cin] = (char)(int)q;
    }
    __syncthreads();
    // write 136 16-B chunks: c = (c32*2+kb)*34 + xs
    char* row = qx + (size_t)(b * HP + y + 1) * (XCH * 16);
    if (t < XCH) {
      const int c32 = t / 68;
      const int r   = t - c32 * 68;
      const int kb  = r / 34;
      const int xs  = r - kb * 34;
      uint4 v; v.x = v.y = v.z = v.w = 0;
      if (xs >= 1 && xs <= 32)
        v = *(const uint4*)(&lds[(xs - 1) * 80 + c32 * 32 + kb * 16]);
      *(uint4*)(row + t * 16) = v;
    }
  } else if (bb < 544) {
    // zero halo rows: idx -> (b, yy in {0,33})
    const int idx = bb - 512;
    const int b = idx >> 1, yy = (idx & 1) ? 33 : 0;
    char* row = qx + (size_t)(b * HP + yy) * (XCH * 16);
    uint4 z; z.x = z.y = z.z = z.w = 0;
    if (t < XCH) *(uint4*)(row + t * 16) = z;
  } else {
    const int i = (bb - 544) * 256 + t;     // < 73728
    const float s = wave_max256(bmw) / 127.0f;
    float q = rintf(w[i] / s);
    q = fminf(fmaxf(q, -127.0f), 127.0f);
    // i = ((o*64 + c)*3 + kh)*3 + kw
    const int kw = i % 3; int j = i / 3;
    const int kh = j % 3; j /= 3;
    const int c = j & 63; const int o = j >> 6;
    const int sidx = kh * 3 + kw;
    const int c32 = c >> 5, kb = (c >> 4) & 1, e = c & 15;
    qw[(size_t)(((sidx * 2 + c32) * 2 + kb) * 128 + o) * 16 + e] = (char)(int)q;
  }
}

// ---------------------------------------------------------------------------
// Stage 3: conv as 32x32x32 INT8 MFMA (exact: |q|<=127, i32 accum, partials
// < 2^24). Grid 512 (32 y x 16 b), 4 waves/block (cout groups), 2 blocks/CU.
// Wave = 32 pixels (one row) x 32 couts. Per (s, c32-half): one A-load + one
// B-load (16 B/lane, contiguous 512 B per half-wave) + one MFMA -> 18 MFMA,
// 36 loads per wave (half of R4's bf16 traffic on the binding L1 pipe).
// A frag: A[m=lane&31][k=(lane>>5)*16+j]; B: B[k][n=lane&31].
// D: col=lane&31 (pixel x), row=(reg&3)+8*(reg>>2)+4*(lane>>5) (cout) —
// C/D layout is dtype-independent. Two acc chains (exact integer sum).
// ---------------------------------------------------------------------------
__global__ __launch_bounds__(256, 2) void conv_mfma_kernel(
    const char* __restrict__ qx,  // [16][34][2][2][34][16]
    const char* __restrict__ qw,  // [9][2][2][128][16]
    const float* __restrict__ bmx, const float* __restrict__ bmw,
    const float* __restrict__ bias, float* __restrict__ out) {
  const int lane = threadIdx.x & 63;
  const int wv   = threadIdx.x >> 6;   // cout group
  const int col  = lane & 31;          // pixel x (B) / cout row (A)
  const int kb   = lane >> 5;          // k-half within 32
  const int y    = blockIdx.x;
  const int b    = blockIdx.y;
  const int co0  = wv * 32;

  int16v acc0 = (int16v)0, acc1 = (int16v)0;

  // qx byte offsets: ((((b*34 + y+kh)*2 + c32)*2 + kb)*34 + col+kw)*16
  const char* __restrict__ xp = qx + ((size_t)(b * HP + y) * 4 + kb) * 544 + col * 16;
  // qw byte offsets: (((s*2 + c32)*2 + kb)*128 + co0+col)*16
  const char* __restrict__ wp = qw + (kb * 128 + co0 + col) * 16;

#pragma unroll
  for (int kh = 0; kh < 3; ++kh) {
    const char* __restrict__ xr = xp + (size_t)kh * (4 * 544);
#pragma unroll
    for (int kw = 0; kw < 3; ++kw) {
      const int s = kh * 3 + kw;
#pragma unroll
      for (int c32 = 0; c32 < 2; ++c32) {
        int4v a  = *(const int4v*)(wp + (s * 2 + c32) * 4096);
        int4v bf = *(const int4v*)(xr + c32 * 1088 + kw * 16);
        if (((s * 2 + c32) & 1) == 0)
          acc0 = __builtin_amdgcn_mfma_i32_32x32x32_i8(a, bf, acc0, 0, 0, 0);
        else
          acc1 = __builtin_amdgcn_mfma_i32_32x32x32_i8(a, bf, acc1, 0, 0, 0);
      }
    }
  }

  const float mx = wave_max256(bmx);
  const float mw = wave_max256(bmw);
  const float sc = (mx / 127.0f) * (mw / 127.0f);
#pragma unroll
  for (int r = 0; r < 16; ++r) {
    const int row  = (r & 3) + 8 * (r >> 2) + 4 * kb;
    const int cout = co0 + row;
    out[((b * COUT + cout) << 10) + y * W_ + col] =
        sc * (float)(acc0[r] + acc1[r]) + bias[cout];
  }
}

// ---------------------------------------------------------------------------
extern "C" void kernel_launch(void* const* d_in, const int* in_sizes, int n_in,
                              void* d_out, int out_size, void* d_ws, size_t ws_size,
                              hipStream_t stream) {
  const float* x    = (const float*)d_in[0];
  const float* w    = (const float*)d_in[1];
  const float* bias = (const float*)d_in[2];
  float* out = (float*)d_out;

  // ws: bmx[256] | bmw[256] | qx s8 [16][34][136][16] (1.19 MB) | qw s8 (73.7 KB)
  float* bmx = (float*)d_ws;
  float* bmw = bmx + 256;
  char* qx = (char*)d_ws + 2048;
  char* qw = qx + (size_t)B_ * HP * XCH * 16;

  maxabs_kernel<<<NPB, 256, 0, stream>>>((const float4*)x, (const float4*)w,
                                         bmx, bmw);
  quant_pack_kernel<<<832, 256, 0, stream>>>(x, w, bmx, bmw, qx, qw);
  conv_mfma_kernel<<<dim3(32, 16), 256, 0, stream>>>(qx, qw, bmx, bmw, bias, out);
}